// Round 1
// baseline (3218.682 us; speedup 1.0000x reference)
//
#include <hip/hip_runtime.h>
#include <hip/hip_bf16.h>
#include <float.h>

// VectorQuantizer: inputs [16,4096,256] f32, embeddings [4096,256] f32.
// d_out = [quantized 16777216 f32][loss 1 f32][indices 65536 (written as f32)]
// d_ws  = [esq 4096 f32][loss accumulator 1 f32]
//
// R1 baseline: fp32 vector-ALU fused GEMM+argmin (no fp32 MFMA on CDNA4).
// 1024 WGs x 256 thr; 64 rows/WG; X-tile resident in LDS (64x260 f32),
// E streamed in 64-code tiles. Thread tile 4x4 (strided mapping to dodge
// LDS bank conflicts). Roofline: 1.37e11 FLOP / 157.3 TF = 870 us floor.

#define DDIM 256
#define KCODES 4096
#define NROWS 65536
#define MT 64       // rows per workgroup
#define CTILE 64    // codes per LDS tile
#define STRIDE 260  // padded f32 per row in LDS (16B-aligned, +2-way max conflict)

__global__ __launch_bounds__(64) void esq_kernel(const float* __restrict__ emb,
                                                 float* __restrict__ ws) {
    int c = blockIdx.x;
    int l = threadIdx.x;
    const float4* e4 = (const float4*)(emb + (size_t)c * DDIM);
    float4 v = e4[l];
    float s = v.x * v.x + v.y * v.y + v.z * v.z + v.w * v.w;
#pragma unroll
    for (int off = 32; off >= 1; off >>= 1) s += __shfl_down(s, off);
    if (l == 0) ws[c] = s;
    if (c == 0 && l == 0) ws[KCODES] = 0.0f;  // zero the loss accumulator
}

__global__ __launch_bounds__(256, 1) void vq_kernel(const float* __restrict__ inp,
                                                    const float* __restrict__ emb,
                                                    const float* __restrict__ esq_g,
                                                    float* __restrict__ out,
                                                    float* __restrict__ loss_ws) {
    __shared__ float xs[MT * STRIDE];     // 66,560 B
    __shared__ float es[CTILE * STRIDE];  // 66,560 B
    __shared__ int sidx[MT];

    const int t = threadIdx.x;
    const int tx = t & 15;   // code direction
    const int ty = t >> 4;   // row direction
    const int wg = blockIdx.x;
    const size_t row0 = (size_t)wg * MT;

    // ---- stage X tile (64 rows x 256 dims), row-major padded ----
    {
        const float4* xg = (const float4*)(inp + row0 * DDIM);
#pragma unroll
        for (int it = 0; it < 16; ++it) {
            int f4 = t + 256 * it;
            int row = f4 >> 6, c4 = f4 & 63;
            float4 v = xg[f4];
            *(float4*)&xs[row * STRIDE + 4 * c4] = v;
        }
    }

    float minv[4];
    int mini[4];
#pragma unroll
    for (int i = 0; i < 4; ++i) { minv[i] = FLT_MAX; mini[i] = 0; }

    for (int ct = 0; ct < KCODES / CTILE; ++ct) {
        __syncthreads();  // previous tile's es reads done (also covers xs staging on ct==0)
        // ---- stage E tile ----
        const float4* eg = (const float4*)(emb + (size_t)ct * CTILE * DDIM);
#pragma unroll
        for (int it = 0; it < 16; ++it) {
            int f4 = t + 256 * it;
            int row = f4 >> 6, c4 = f4 & 63;
            float4 v = eg[f4];
            *(float4*)&es[row * STRIDE + 4 * c4] = v;
        }
        float esq[4];
#pragma unroll
        for (int j = 0; j < 4; ++j) esq[j] = esq_g[ct * CTILE + tx + 16 * j];
        __syncthreads();

        float acc[16];
#pragma unroll
        for (int k = 0; k < 16; ++k) acc[k] = 0.0f;

#pragma unroll 4
        for (int d4 = 0; d4 < DDIM / 4; ++d4) {
            float4 xa[4], eb[4];
#pragma unroll
            for (int i = 0; i < 4; ++i)
                xa[i] = *(const float4*)&xs[(ty + 16 * i) * STRIDE + 4 * d4];
#pragma unroll
            for (int j = 0; j < 4; ++j)
                eb[j] = *(const float4*)&es[(tx + 16 * j) * STRIDE + 4 * d4];
#pragma unroll
            for (int i = 0; i < 4; ++i)
#pragma unroll
                for (int j = 0; j < 4; ++j) {
                    acc[i * 4 + j] += xa[i].x * eb[j].x;
                    acc[i * 4 + j] += xa[i].y * eb[j].y;
                    acc[i * 4 + j] += xa[i].z * eb[j].z;
                    acc[i * 4 + j] += xa[i].w * eb[j].w;
                }
        }

        // running argmin: dist = |e|^2 - 2 x.e  (|x|^2 is row-constant)
#pragma unroll
        for (int j = 0; j < 4; ++j) {
            int code = ct * CTILE + tx + 16 * j;
#pragma unroll
            for (int i = 0; i < 4; ++i) {
                float dist = esq[j] - 2.0f * acc[i * 4 + j];
                if (dist < minv[i]) { minv[i] = dist; mini[i] = code; }
            }
        }
    }

    // ---- cross-lane argmin reduce: 16 lanes (same ty) share rows ty+16i ----
#pragma unroll
    for (int i = 0; i < 4; ++i) {
        float v = minv[i];
        int k = mini[i];
#pragma unroll
        for (int off = 1; off < 16; off <<= 1) {
            float ov = __shfl_xor(v, off);
            int ok = __shfl_xor(k, off);
            if (ov < v || (ov == v && ok < k)) { v = ov; k = ok; }  // numpy first-index tie-break
        }
        if (tx == 0) {
            int row = ty + 16 * i;
            sidx[row] = k;
            out[(size_t)16777216 + 1 + row0 + row] = (float)k;
        }
    }
    __syncthreads();

    // ---- gather quantized + loss ----
    float lsum = 0.0f;
    const float4* embf4 = (const float4*)emb;
    float4* outq = (float4*)out;
#pragma unroll
    for (int it = 0; it < 16; ++it) {
        int f4 = t + 256 * it;
        int row = f4 >> 6, c4 = f4 & 63;
        int k = sidx[row];
        float4 e = embf4[(size_t)k * 64 + c4];
        float4 x = *(const float4*)&xs[row * STRIDE + 4 * c4];
        float dx = e.x - x.x, dy = e.y - x.y, dz = e.z - x.z, dw = e.w - x.w;
        lsum += dx * dx + dy * dy + dz * dz + dw * dw;
        outq[row0 * 64 + f4] = e;
    }
#pragma unroll
    for (int off = 32; off >= 1; off >>= 1) lsum += __shfl_down(lsum, off);
    if ((t & 63) == 0) atomicAdd(loss_ws, lsum);
}

__global__ void loss_kernel(const float* __restrict__ ws, float* __restrict__ out) {
    out[16777216] = ws[KCODES] * (1.0f / 16777216.0f);
}

extern "C" void kernel_launch(void* const* d_in, const int* in_sizes, int n_in,
                              void* d_out, int out_size, void* d_ws, size_t ws_size,
                              hipStream_t stream) {
    const float* inp = (const float*)d_in[0];
    const float* emb = (const float*)d_in[1];
    float* out = (float*)d_out;
    float* ws = (float*)d_ws;

    hipLaunchKernelGGL(esq_kernel, dim3(KCODES), dim3(64), 0, stream, emb, ws);
    hipLaunchKernelGGL(vq_kernel, dim3(NROWS / MT), dim3(256), 0, stream,
                       inp, emb, ws, out, ws + KCODES);
    hipLaunchKernelGGL(loss_kernel, dim3(1), dim3(1), 0, stream, ws, out);
}

// Round 3
// 1658.183 us; speedup vs baseline: 1.9411x; 1.9411x over previous
//
#include <hip/hip_runtime.h>
#include <float.h>
#include <stdint.h>

// VectorQuantizer R3: bf16x3 MFMA distance GEMM + fp32 near-tie recheck.
// R2→R3 fix: per-wave partial slots (ni*2+wn) — R2 had two waves (wn=0/1,
// same wm) racing on one pmin2/pidx slot, dropping half of each block's
// codes. Now 64 partial sets per row, reduced in vq_reduce.
//
// d_out = [quantized 16777216 f32][loss 1 f32][indices 65536 f32]
//   (quantized region doubles as scratch for per-wave argmin partials:
//    pmin2 = 8388608 floats, pidx = 4194304 ints → 12582912 < 16777216)
// d_ws (floats): [esq 4096][loss acc 1][flag count 1][flags 65536][idx_final 65536]

#define DDIM 256
#define KCODES 4096
#define NROWS 65536
#define QSIZE 16777216
#define NSLOT 64           // (KCODES/128) * 2 waves in the code direction
#define GAP_THRESH 0.02f   // bf16x3 dist error ~1e-3 worst case; 20x margin

typedef short bf16x8 __attribute__((ext_vector_type(8)));
typedef float f32x4 __attribute__((ext_vector_type(4)));

// ---- esq + init: |e|^2 per code, zero loss & flag counters ----
__global__ __launch_bounds__(64) void esq_kernel(const float* __restrict__ emb,
                                                 float* __restrict__ ws) {
    int c = blockIdx.x, l = threadIdx.x;
    const float4* e4 = (const float4*)(emb + (size_t)c * DDIM);
    float4 v = e4[l];
    float s = v.x * v.x + v.y * v.y + v.z * v.z + v.w * v.w;
#pragma unroll
    for (int off = 32; off >= 1; off >>= 1) s += __shfl_down(s, off);
    if (l == 0) ws[c] = s;
    if (c == 0 && l == 0) { ws[KCODES] = 0.0f; ((int*)ws)[KCODES + 1] = 0; }
}

// split fp32 -> (hi bf16 = RTZ top16, lo bf16 = RTZ(x - hi)); pack 8 elems
__device__ __forceinline__ void stage8(const float* __restrict__ p,
                                       short* __restrict__ dh,
                                       short* __restrict__ dl) {
    float4 a = *(const float4*)p;
    float4 b = *(const float4*)(p + 4);
    float f[8] = {a.x, a.y, a.z, a.w, b.x, b.y, b.z, b.w};
    uint32_t hu[8], lu[8];
#pragma unroll
    for (int k = 0; k < 8; ++k) {
        uint32_t u = __float_as_uint(f[k]);
        uint32_t h = u & 0xFFFF0000u;
        hu[k] = h;
        lu[k] = __float_as_uint(f[k] - __uint_as_float(h));
    }
    uint4 hv, lv;
    hv.x = __builtin_amdgcn_perm(hu[1], hu[0], 0x07060302u);
    hv.y = __builtin_amdgcn_perm(hu[3], hu[2], 0x07060302u);
    hv.z = __builtin_amdgcn_perm(hu[5], hu[4], 0x07060302u);
    hv.w = __builtin_amdgcn_perm(hu[7], hu[6], 0x07060302u);
    lv.x = __builtin_amdgcn_perm(lu[1], lu[0], 0x07060302u);
    lv.y = __builtin_amdgcn_perm(lu[3], lu[2], 0x07060302u);
    lv.z = __builtin_amdgcn_perm(lu[5], lu[4], 0x07060302u);
    lv.w = __builtin_amdgcn_perm(lu[7], lu[6], 0x07060302u);
    *(uint4*)dh = hv;
    *(uint4*)dl = lv;
}

// ---- main GEMM: 128x128 tile, K=8 chunks of 32 dims, 3 bf16 passes/chunk ----
__global__ __launch_bounds__(256, 2) void vq_gemm(const float* __restrict__ inp,
                                                  const float* __restrict__ emb,
                                                  const float* __restrict__ esq,
                                                  float2* __restrict__ pmin2,
                                                  int* __restrict__ pidx) {
    __shared__ __align__(16) short Ah[128 * 40];
    __shared__ __align__(16) short Al[128 * 40];
    __shared__ __align__(16) short Bh[128 * 40];
    __shared__ __align__(16) short Bl[128 * 40];

    const int t = threadIdx.x;
    const int mi = blockIdx.x >> 5, ni = blockIdx.x & 31;
    const size_t row0 = (size_t)mi * 128;
    const int col0 = ni * 128;
    const int lane = t & 63, wave = t >> 6;
    const int wm = wave >> 1, wn = wave & 1;
    const int n15 = lane & 15, quad = lane >> 4;

    f32x4 acc[4][4];
#pragma unroll
    for (int i = 0; i < 4; ++i)
#pragma unroll
        for (int j = 0; j < 4; ++j) {
            acc[i][j][0] = 0.f; acc[i][j][1] = 0.f;
            acc[i][j][2] = 0.f; acc[i][j][3] = 0.f;
        }

    for (int ch = 0; ch < 8; ++ch) {
        const int d0 = ch * 32;
        __syncthreads();
        // stage A (input rows) and B (codes): 512 8-dim groups each
#pragma unroll
        for (int it = 0; it < 2; ++it) {
            int idx = t + 256 * it;
            int r = idx >> 2, c8 = idx & 3;
            stage8(inp + (row0 + r) * DDIM + d0 + 8 * c8,
                   &Ah[r * 40 + 8 * c8], &Al[r * 40 + 8 * c8]);
            stage8(emb + (size_t)(col0 + r) * DDIM + d0 + 8 * c8,
                   &Bh[r * 40 + 8 * c8], &Bl[r * 40 + 8 * c8]);
        }
        __syncthreads();

        bf16x8 ah[4], al[4], bh[4], bl[4];
#pragma unroll
        for (int i = 0; i < 4; ++i) {
            int off = (wm * 64 + i * 16 + n15) * 40 + quad * 8;
            ah[i] = *(const bf16x8*)&Ah[off];
            al[i] = *(const bf16x8*)&Al[off];
        }
#pragma unroll
        for (int j = 0; j < 4; ++j) {
            int off = (wn * 64 + j * 16 + n15) * 40 + quad * 8;
            bh[j] = *(const bf16x8*)&Bh[off];
            bl[j] = *(const bf16x8*)&Bl[off];
        }
#pragma unroll
        for (int i = 0; i < 4; ++i)
#pragma unroll
            for (int j = 0; j < 4; ++j) {
                acc[i][j] = __builtin_amdgcn_mfma_f32_16x16x32_bf16(ah[i], bh[j], acc[i][j], 0, 0, 0);
                acc[i][j] = __builtin_amdgcn_mfma_f32_16x16x32_bf16(ah[i], bl[j], acc[i][j], 0, 0, 0);
                acc[i][j] = __builtin_amdgcn_mfma_f32_16x16x32_bf16(al[i], bh[j], acc[i][j], 0, 0, 0);
            }
    }

    // ---- epilogue: per-row top-2 argmin over this wave's 64 codes ----
    float esqv[4];
#pragma unroll
    for (int j = 0; j < 4; ++j) esqv[j] = esq[col0 + wn * 64 + j * 16 + n15];

#pragma unroll
    for (int i = 0; i < 4; ++i) {
#pragma unroll
        for (int reg = 0; reg < 4; ++reg) {
            float m1 = FLT_MAX, m2 = FLT_MAX;
            int bi = 0;
#pragma unroll
            for (int j = 0; j < 4; ++j) {
                float d = esqv[j] - 2.0f * acc[i][j][reg];
                int code = col0 + wn * 64 + j * 16 + n15;
                if (d < m1) { m2 = m1; m1 = d; bi = code; }
                else if (d < m2) { m2 = d; }
            }
            // merge across the 16 lanes sharing this row (xor bits 0-3)
#pragma unroll
            for (int off = 1; off < 16; off <<= 1) {
                float om1 = __shfl_xor(m1, off);
                float om2 = __shfl_xor(m2, off);
                int obi = __shfl_xor(bi, off);
                bool take = (om1 < m1) || (om1 == m1 && obi < bi);
                if (take) { m2 = fminf(m1, om2); m1 = om1; bi = obi; }
                else      { m2 = fminf(om1, m2); }
            }
            if (n15 == 0) {
                int rg = (int)row0 + wm * 64 + i * 16 + quad * 4 + reg;
                int slot = ni * 2 + wn;  // per-wave slot: no cross-wave race
                pmin2[(size_t)slot * NROWS + rg] = make_float2(m1, m2);
                pidx[(size_t)slot * NROWS + rg] = bi;
            }
        }
    }
}

// ---- reduce 64 per-wave partials per row; flag near-ties ----
__global__ __launch_bounds__(256) void vq_reduce(const float2* __restrict__ pmin2,
                                                 const int* __restrict__ pidx,
                                                 int* __restrict__ idx_final,
                                                 int* __restrict__ flags,
                                                 int* __restrict__ fcount) {
    int row = blockIdx.x * 256 + threadIdx.x;
    float m1 = FLT_MAX, m2 = FLT_MAX;
    int bi = 0;
    for (int nb = 0; nb < NSLOT; ++nb) {
        float2 p = pmin2[(size_t)nb * NROWS + row];
        int pi = pidx[(size_t)nb * NROWS + row];
        if (p.x < m1) { m2 = fminf(m1, p.y); m1 = p.x; bi = pi; }
        else          { m2 = fminf(m2, p.x); }
    }
    idx_final[row] = bi;
    if (m2 - m1 < GAP_THRESH) {
        int s = atomicAdd(fcount, 1);
        flags[s] = row;
    }
}

// ---- fp32 recheck of flagged rows (replicates R1's passing fp32 semantics) ----
__global__ __launch_bounds__(256) void vq_recheck(const float* __restrict__ inp,
                                                  const float* __restrict__ emb,
                                                  const float* __restrict__ esq,
                                                  const int* __restrict__ flags,
                                                  const int* __restrict__ fcount,
                                                  int* __restrict__ idx_final) {
    __shared__ float4 xs[64];
    __shared__ float sv[4];
    __shared__ int si[4];
    const int t = threadIdx.x;
    const int cnt = *fcount;
    for (int f = blockIdx.x; f < cnt; f += gridDim.x) {
        int row = flags[f];
        __syncthreads();
        if (t < 64) xs[t] = ((const float4*)inp)[(size_t)row * 64 + t];
        __syncthreads();
        float m1 = FLT_MAX;
        int bi = 0x7FFFFFFF;
        for (int cc = 0; cc < 16; ++cc) {
            int c = cc * 256 + t;
            const float4* e4 = (const float4*)emb + (size_t)c * 64;
            float dot = 0.f;
            for (int d4 = 0; d4 < 64; ++d4) {
                float4 e = e4[d4];
                float4 x = xs[d4];
                dot += e.x * x.x; dot += e.y * x.y;
                dot += e.z * x.z; dot += e.w * x.w;
            }
            float d = esq[c] - 2.0f * dot;
            if (d < m1 || (d == m1 && c < bi)) { m1 = d; bi = c; }
        }
#pragma unroll
        for (int off = 1; off < 64; off <<= 1) {
            float om = __shfl_xor(m1, off);
            int ob = __shfl_xor(bi, off);
            if (om < m1 || (om == m1 && ob < bi)) { m1 = om; bi = ob; }
        }
        if ((t & 63) == 0) { sv[t >> 6] = m1; si[t >> 6] = bi; }
        __syncthreads();
        if (t == 0) {
            for (int w = 1; w < 4; ++w)
                if (sv[w] < m1 || (sv[w] == m1 && si[w] < bi)) { m1 = sv[w]; bi = si[w]; }
            idx_final[row] = bi;
        }
    }
}

// ---- gather quantized, write indices, accumulate loss ----
__global__ __launch_bounds__(256) void vq_gather(const float* __restrict__ inp,
                                                 const float* __restrict__ emb,
                                                 const int* __restrict__ idx_final,
                                                 float* __restrict__ out,
                                                 float* __restrict__ lacc) {
    size_t gid = (size_t)blockIdx.x * 256 + threadIdx.x;
    int row = (int)(gid >> 6), c4 = (int)(gid & 63);
    int k = idx_final[row];
    float4 e = ((const float4*)emb)[(size_t)k * 64 + c4];
    float4 x = ((const float4*)inp)[gid];
    ((float4*)out)[gid] = e;
    float dx = e.x - x.x, dy = e.y - x.y, dz = e.z - x.z, dw = e.w - x.w;
    float ls = dx * dx + dy * dy + dz * dz + dw * dw;
#pragma unroll
    for (int off = 32; off >= 1; off >>= 1) ls += __shfl_down(ls, off);
    if ((threadIdx.x & 63) == 0) atomicAdd(lacc, ls);
    if (c4 == 0) out[(size_t)QSIZE + 1 + row] = (float)k;
}

__global__ void loss_kernel(const float* __restrict__ ws, float* __restrict__ out) {
    out[QSIZE] = ws[KCODES] * (1.0f / 16777216.0f);
}

extern "C" void kernel_launch(void* const* d_in, const int* in_sizes, int n_in,
                              void* d_out, int out_size, void* d_ws, size_t ws_size,
                              hipStream_t stream) {
    const float* inp = (const float*)d_in[0];
    const float* emb = (const float*)d_in[1];
    float* out = (float*)d_out;
    float* ws = (float*)d_ws;

    // ws layout (element offsets): esq [0,4096), lacc 4096, fcount 4097,
    // flags [4098, 69634), idx_final [69634, 135170)
    float* esq = ws;
    float* lacc = ws + KCODES;
    int* fcount = (int*)ws + KCODES + 1;
    int* flags = (int*)ws + KCODES + 2;
    int* idx_final = (int*)ws + KCODES + 2 + NROWS;

    // big partials live in d_out's quantized region (overwritten by vq_gather)
    float2* pmin2 = (float2*)out;                 // [0, 8388608) floats
    int* pidx = (int*)out + 8388608;              // [8388608, 12582912) floats

    hipLaunchKernelGGL(esq_kernel, dim3(KCODES), dim3(64), 0, stream, emb, ws);
    hipLaunchKernelGGL(vq_gemm, dim3((NROWS / 128) * 32), dim3(256), 0, stream,
                       inp, emb, esq, pmin2, pidx);
    hipLaunchKernelGGL(vq_reduce, dim3(NROWS / 256), dim3(256), 0, stream,
                       pmin2, pidx, idx_final, flags, fcount);
    hipLaunchKernelGGL(vq_recheck, dim3(256), dim3(256), 0, stream,
                       inp, emb, esq, flags, fcount, idx_final);
    hipLaunchKernelGGL(vq_gather, dim3(QSIZE / 4 / 256), dim3(256), 0, stream,
                       inp, emb, idx_final, out, lacc);
    hipLaunchKernelGGL(loss_kernel, dim3(1), dim3(1), 0, stream, ws, out);
}

// Round 4
// 853.191 us; speedup vs baseline: 3.7725x; 1.9435x over previous
//
#include <hip/hip_runtime.h>
#include <float.h>
#include <stdint.h>

// VectorQuantizer R4: bf16x3 MFMA distance GEMM + fp32 near-tie recheck.
// R3→R4 fix: vq_gather's 65536 single-address atomicAdds (834 us, 12.7 ns
// each, serialized) replaced by per-block LDS reduction -> 16384 partials
// in ws -> loss_kernel reduces. Zero atomics on the loss path.
//
// d_out = [quantized 16777216 f32][loss 1 f32][indices 65536 f32]
//   (quantized region doubles as scratch for per-wave argmin partials:
//    pmin2 = 8388608 floats, pidx = 4194304 ints → 12582912 < 16777216)
// d_ws (element offsets): esq [0,4096) | fcount 4097 (int) |
//   flags [4098,69634) (int) | idx_final [69634,135170) (int) |
//   loss partials [135170,151554)

#define DDIM 256
#define KCODES 4096
#define NROWS 65536
#define QSIZE 16777216
#define NSLOT 64           // (KCODES/128) * 2 waves in the code direction
#define NLBLK 16384        // vq_gather grid size = loss partial count
#define GAP_THRESH 0.02f   // bf16x3 dist error ~1e-3 worst case; 20x margin

typedef short bf16x8 __attribute__((ext_vector_type(8)));
typedef float f32x4 __attribute__((ext_vector_type(4)));

// ---- esq + init: |e|^2 per code, zero flag counter ----
__global__ __launch_bounds__(64) void esq_kernel(const float* __restrict__ emb,
                                                 float* __restrict__ ws) {
    int c = blockIdx.x, l = threadIdx.x;
    const float4* e4 = (const float4*)(emb + (size_t)c * DDIM);
    float4 v = e4[l];
    float s = v.x * v.x + v.y * v.y + v.z * v.z + v.w * v.w;
#pragma unroll
    for (int off = 32; off >= 1; off >>= 1) s += __shfl_down(s, off);
    if (l == 0) ws[c] = s;
    if (c == 0 && l == 0) { ((int*)ws)[KCODES + 1] = 0; }
}

// split fp32 -> (hi bf16 = RTZ top16, lo bf16 = RTZ(x - hi)); pack 8 elems
__device__ __forceinline__ void stage8(const float* __restrict__ p,
                                       short* __restrict__ dh,
                                       short* __restrict__ dl) {
    float4 a = *(const float4*)p;
    float4 b = *(const float4*)(p + 4);
    float f[8] = {a.x, a.y, a.z, a.w, b.x, b.y, b.z, b.w};
    uint32_t hu[8], lu[8];
#pragma unroll
    for (int k = 0; k < 8; ++k) {
        uint32_t u = __float_as_uint(f[k]);
        uint32_t h = u & 0xFFFF0000u;
        hu[k] = h;
        lu[k] = __float_as_uint(f[k] - __uint_as_float(h));
    }
    uint4 hv, lv;
    hv.x = __builtin_amdgcn_perm(hu[1], hu[0], 0x07060302u);
    hv.y = __builtin_amdgcn_perm(hu[3], hu[2], 0x07060302u);
    hv.z = __builtin_amdgcn_perm(hu[5], hu[4], 0x07060302u);
    hv.w = __builtin_amdgcn_perm(hu[7], hu[6], 0x07060302u);
    lv.x = __builtin_amdgcn_perm(lu[1], lu[0], 0x07060302u);
    lv.y = __builtin_amdgcn_perm(lu[3], lu[2], 0x07060302u);
    lv.z = __builtin_amdgcn_perm(lu[5], lu[4], 0x07060302u);
    lv.w = __builtin_amdgcn_perm(lu[7], lu[6], 0x07060302u);
    *(uint4*)dh = hv;
    *(uint4*)dl = lv;
}

// ---- main GEMM: 128x128 tile, K=8 chunks of 32 dims, 3 bf16 passes/chunk ----
__global__ __launch_bounds__(256, 2) void vq_gemm(const float* __restrict__ inp,
                                                  const float* __restrict__ emb,
                                                  const float* __restrict__ esq,
                                                  float2* __restrict__ pmin2,
                                                  int* __restrict__ pidx) {
    __shared__ __align__(16) short Ah[128 * 40];
    __shared__ __align__(16) short Al[128 * 40];
    __shared__ __align__(16) short Bh[128 * 40];
    __shared__ __align__(16) short Bl[128 * 40];

    const int t = threadIdx.x;
    const int mi = blockIdx.x >> 5, ni = blockIdx.x & 31;
    const size_t row0 = (size_t)mi * 128;
    const int col0 = ni * 128;
    const int lane = t & 63, wave = t >> 6;
    const int wm = wave >> 1, wn = wave & 1;
    const int n15 = lane & 15, quad = lane >> 4;

    f32x4 acc[4][4];
#pragma unroll
    for (int i = 0; i < 4; ++i)
#pragma unroll
        for (int j = 0; j < 4; ++j) {
            acc[i][j][0] = 0.f; acc[i][j][1] = 0.f;
            acc[i][j][2] = 0.f; acc[i][j][3] = 0.f;
        }

    for (int ch = 0; ch < 8; ++ch) {
        const int d0 = ch * 32;
        __syncthreads();
        // stage A (input rows) and B (codes): 512 8-dim groups each
#pragma unroll
        for (int it = 0; it < 2; ++it) {
            int idx = t + 256 * it;
            int r = idx >> 2, c8 = idx & 3;
            stage8(inp + (row0 + r) * DDIM + d0 + 8 * c8,
                   &Ah[r * 40 + 8 * c8], &Al[r * 40 + 8 * c8]);
            stage8(emb + (size_t)(col0 + r) * DDIM + d0 + 8 * c8,
                   &Bh[r * 40 + 8 * c8], &Bl[r * 40 + 8 * c8]);
        }
        __syncthreads();

        bf16x8 ah[4], al[4], bh[4], bl[4];
#pragma unroll
        for (int i = 0; i < 4; ++i) {
            int off = (wm * 64 + i * 16 + n15) * 40 + quad * 8;
            ah[i] = *(const bf16x8*)&Ah[off];
            al[i] = *(const bf16x8*)&Al[off];
        }
#pragma unroll
        for (int j = 0; j < 4; ++j) {
            int off = (wn * 64 + j * 16 + n15) * 40 + quad * 8;
            bh[j] = *(const bf16x8*)&Bh[off];
            bl[j] = *(const bf16x8*)&Bl[off];
        }
#pragma unroll
        for (int i = 0; i < 4; ++i)
#pragma unroll
            for (int j = 0; j < 4; ++j) {
                acc[i][j] = __builtin_amdgcn_mfma_f32_16x16x32_bf16(ah[i], bh[j], acc[i][j], 0, 0, 0);
                acc[i][j] = __builtin_amdgcn_mfma_f32_16x16x32_bf16(ah[i], bl[j], acc[i][j], 0, 0, 0);
                acc[i][j] = __builtin_amdgcn_mfma_f32_16x16x32_bf16(al[i], bh[j], acc[i][j], 0, 0, 0);
            }
    }

    // ---- epilogue: per-row top-2 argmin over this wave's 64 codes ----
    float esqv[4];
#pragma unroll
    for (int j = 0; j < 4; ++j) esqv[j] = esq[col0 + wn * 64 + j * 16 + n15];

#pragma unroll
    for (int i = 0; i < 4; ++i) {
#pragma unroll
        for (int reg = 0; reg < 4; ++reg) {
            float m1 = FLT_MAX, m2 = FLT_MAX;
            int bi = 0;
#pragma unroll
            for (int j = 0; j < 4; ++j) {
                float d = esqv[j] - 2.0f * acc[i][j][reg];
                int code = col0 + wn * 64 + j * 16 + n15;
                if (d < m1) { m2 = m1; m1 = d; bi = code; }
                else if (d < m2) { m2 = d; }
            }
            // merge across the 16 lanes sharing this row (xor bits 0-3)
#pragma unroll
            for (int off = 1; off < 16; off <<= 1) {
                float om1 = __shfl_xor(m1, off);
                float om2 = __shfl_xor(m2, off);
                int obi = __shfl_xor(bi, off);
                bool take = (om1 < m1) || (om1 == m1 && obi < bi);
                if (take) { m2 = fminf(m1, om2); m1 = om1; bi = obi; }
                else      { m2 = fminf(om1, m2); }
            }
            if (n15 == 0) {
                int rg = (int)row0 + wm * 64 + i * 16 + quad * 4 + reg;
                int slot = ni * 2 + wn;  // per-wave slot: no cross-wave race
                pmin2[(size_t)slot * NROWS + rg] = make_float2(m1, m2);
                pidx[(size_t)slot * NROWS + rg] = bi;
            }
        }
    }
}

// ---- reduce 64 per-wave partials per row; flag near-ties ----
__global__ __launch_bounds__(256) void vq_reduce(const float2* __restrict__ pmin2,
                                                 const int* __restrict__ pidx,
                                                 int* __restrict__ idx_final,
                                                 int* __restrict__ flags,
                                                 int* __restrict__ fcount) {
    int row = blockIdx.x * 256 + threadIdx.x;
    float m1 = FLT_MAX, m2 = FLT_MAX;
    int bi = 0;
    for (int nb = 0; nb < NSLOT; ++nb) {
        float2 p = pmin2[(size_t)nb * NROWS + row];
        int pi = pidx[(size_t)nb * NROWS + row];
        if (p.x < m1) { m2 = fminf(m1, p.y); m1 = p.x; bi = pi; }
        else          { m2 = fminf(m2, p.x); }
    }
    idx_final[row] = bi;
    if (m2 - m1 < GAP_THRESH) {
        int s = atomicAdd(fcount, 1);
        flags[s] = row;
    }
}

// ---- fp32 recheck of flagged rows (replicates R1's passing fp32 semantics) ----
__global__ __launch_bounds__(256) void vq_recheck(const float* __restrict__ inp,
                                                  const float* __restrict__ emb,
                                                  const float* __restrict__ esq,
                                                  const int* __restrict__ flags,
                                                  const int* __restrict__ fcount,
                                                  int* __restrict__ idx_final) {
    __shared__ float4 xs[64];
    __shared__ float sv[4];
    __shared__ int si[4];
    const int t = threadIdx.x;
    const int cnt = *fcount;
    for (int f = blockIdx.x; f < cnt; f += gridDim.x) {
        int row = flags[f];
        __syncthreads();
        if (t < 64) xs[t] = ((const float4*)inp)[(size_t)row * 64 + t];
        __syncthreads();
        float m1 = FLT_MAX;
        int bi = 0x7FFFFFFF;
        for (int cc = 0; cc < 16; ++cc) {
            int c = cc * 256 + t;
            const float4* e4 = (const float4*)emb + (size_t)c * 64;
            float dot = 0.f;
            for (int d4 = 0; d4 < 64; ++d4) {
                float4 e = e4[d4];
                float4 x = xs[d4];
                dot += e.x * x.x; dot += e.y * x.y;
                dot += e.z * x.z; dot += e.w * x.w;
            }
            float d = esq[c] - 2.0f * dot;
            if (d < m1 || (d == m1 && c < bi)) { m1 = d; bi = c; }
        }
#pragma unroll
        for (int off = 1; off < 64; off <<= 1) {
            float om = __shfl_xor(m1, off);
            int ob = __shfl_xor(bi, off);
            if (om < m1 || (om == m1 && ob < bi)) { m1 = om; bi = ob; }
        }
        if ((t & 63) == 0) { sv[t >> 6] = m1; si[t >> 6] = bi; }
        __syncthreads();
        if (t == 0) {
            for (int w = 1; w < 4; ++w)
                if (sv[w] < m1 || (sv[w] == m1 && si[w] < bi)) { m1 = sv[w]; bi = si[w]; }
            idx_final[row] = bi;
        }
    }
}

// ---- gather quantized, write indices, per-block loss partial (NO atomics) ----
__global__ __launch_bounds__(256) void vq_gather(const float* __restrict__ inp,
                                                 const float* __restrict__ emb,
                                                 const int* __restrict__ idx_final,
                                                 float* __restrict__ out,
                                                 float* __restrict__ loss_part) {
    __shared__ float wsum[4];
    size_t gid = (size_t)blockIdx.x * 256 + threadIdx.x;
    int row = (int)(gid >> 6), c4 = (int)(gid & 63);
    int k = idx_final[row];
    float4 e = ((const float4*)emb)[(size_t)k * 64 + c4];
    float4 x = ((const float4*)inp)[gid];
    ((float4*)out)[gid] = e;
    float dx = e.x - x.x, dy = e.y - x.y, dz = e.z - x.z, dw = e.w - x.w;
    float ls = dx * dx + dy * dy + dz * dz + dw * dw;
#pragma unroll
    for (int off = 32; off >= 1; off >>= 1) ls += __shfl_down(ls, off);
    if ((threadIdx.x & 63) == 0) wsum[threadIdx.x >> 6] = ls;
    if (c4 == 0) out[(size_t)QSIZE + 1 + row] = (float)k;
    __syncthreads();
    if (threadIdx.x == 0)
        loss_part[blockIdx.x] = wsum[0] + wsum[1] + wsum[2] + wsum[3];
}

// ---- final loss: reduce 16384 block partials ----
__global__ __launch_bounds__(256) void loss_kernel(const float* __restrict__ loss_part,
                                                   float* __restrict__ out) {
    __shared__ float sw[4];
    int t = threadIdx.x;
    float s = 0.0f;
    for (int i = t; i < NLBLK; i += 256) s += loss_part[i];
#pragma unroll
    for (int off = 32; off >= 1; off >>= 1) s += __shfl_down(s, off);
    if ((t & 63) == 0) sw[t >> 6] = s;
    __syncthreads();
    if (t == 0)
        out[QSIZE] = (sw[0] + sw[1] + sw[2] + sw[3]) * (1.0f / 16777216.0f);
}

extern "C" void kernel_launch(void* const* d_in, const int* in_sizes, int n_in,
                              void* d_out, int out_size, void* d_ws, size_t ws_size,
                              hipStream_t stream) {
    const float* inp = (const float*)d_in[0];
    const float* emb = (const float*)d_in[1];
    float* out = (float*)d_out;
    float* ws = (float*)d_ws;

    float* esq = ws;
    int* fcount = (int*)ws + KCODES + 1;
    int* flags = (int*)ws + KCODES + 2;
    int* idx_final = (int*)ws + KCODES + 2 + NROWS;
    float* loss_part = ws + KCODES + 2 + 2 * NROWS;  // 16384 floats

    // big partials live in d_out's quantized region (overwritten by vq_gather)
    float2* pmin2 = (float2*)out;                 // [0, 8388608) floats
    int* pidx = (int*)out + 8388608;              // [8388608, 12582912) floats

    hipLaunchKernelGGL(esq_kernel, dim3(KCODES), dim3(64), 0, stream, emb, ws);
    hipLaunchKernelGGL(vq_gemm, dim3((NROWS / 128) * 32), dim3(256), 0, stream,
                       inp, emb, esq, pmin2, pidx);
    hipLaunchKernelGGL(vq_reduce, dim3(NROWS / 256), dim3(256), 0, stream,
                       pmin2, pidx, idx_final, flags, fcount);
    hipLaunchKernelGGL(vq_recheck, dim3(256), dim3(256), 0, stream,
                       inp, emb, esq, flags, fcount, idx_final);
    hipLaunchKernelGGL(vq_gather, dim3(NLBLK), dim3(256), 0, stream,
                       inp, emb, idx_final, out, loss_part);
    hipLaunchKernelGGL(loss_kernel, dim3(1), dim3(256), 0, stream, loss_part, out);
}